// Round 1
// baseline (1175.616 us; speedup 1.0000x reference)
//
#include <hip/hip_runtime.h>

// GPUHungarianMatcher R10 — exact replication of the reference's degenerate
// "_lsa" (minv reset every inner iteration => chain-Dijkstra). One block
// (4 waves) per batch. R10 = R9 + two chain-shorteners:
//  (1) colDat moved from LDS into owner-thread REGISTERS (cdu/cdx/cdy[8]).
//      The per-lane winner's cd is selected by a static cndmask tree (bk
//      bits), and the WINNING LANE writes a 32B mailbox {key,idx,u,tx,ty}.
//      Post-barrier: 8 independent uniform ds_read_b128 + tournament — the
//      dependent colDat ds_read (~120cy, address from mailbox) is deleted.
//  (2) per-row epilogue: the serial v-update loop (S iters x 2 dependent LDS
//      reads) and the colDat refresh are replaced by parallel scatter
//      mailboxes vdelta[8][256] (f64, 0.0 = no-op) and cdSlot[8][256]
//      (16B, sentinel tx=-2; stale slots re-apply idempotently). Writers are
//      the path threads; owners read 8 fixed, contiguous (conflict-free)
//      slots. visCol/visD are gone.
//
// Exactness invariants (unchanged from the R2-R9 absmax-0 lineage):
//  * cost fp32: fabsf(qx-tX)+fabsf(qy-tY)+np_, reduced fp64: ((double)cf-u)-v
//  * scans read only PRE-search u/v (path rows/cols distinct, p injective)
//  * argmin: fmin tree + ==-mask + ctz = np.argmin first occurrence
//  * pairwise tournament: left wins ties at every level (same winner as the
//    left-to-right scan); wave level: DPP min on khi + ballot, exact-tie
//    slow path resolves (klo, idx) lexicographic
//  * u update: single add of prefix-difference on pre-search u (recU)
//  * v update: vreg += -(Dfin - recD)  ==  vreg -= (Dfin - recD) bitwise;
//    vreg is never -0.0, so the unconditional +0.0 for untouched columns is
//    a bitwise no-op
//  * softmax bitwise-identical to the R2 tree (same thread mapping)
//  * free-flag: cdx[k] = -1.0f iff column free (real tx >= 0, sentinel -2)

constexpr int B = 8;
constexpr int Q = 2048;        // columns (queries)
constexpr int T = 256;         // rows (targets)
constexpr int NT = 256;        // threads per block (4 waves)
constexpr int KPT = Q / NT;    // 8 columns per thread, j = 1 + tid + k*256
constexpr int NW = NT / 64;
constexpr double DINF = 1e300;

struct __align__(16) CD { double u; float tx, ty; };   // one ds_read_b128

__device__ __forceinline__ unsigned wave_min_u32_dpp(unsigned a) {
  // full-wave u32 min: row_shr 1,2,4,8 then row_bcast15, row_bcast31;
  // invalid source lanes keep old (bound_ctrl=false, masks 0xf) = identity.
  int v = (int)a, t;
  t = __builtin_amdgcn_update_dpp(v, v, 0x111, 0xf, 0xf, false);
  v = ((unsigned)t < (unsigned)v) ? t : v;
  t = __builtin_amdgcn_update_dpp(v, v, 0x112, 0xf, 0xf, false);
  v = ((unsigned)t < (unsigned)v) ? t : v;
  t = __builtin_amdgcn_update_dpp(v, v, 0x114, 0xf, 0xf, false);
  v = ((unsigned)t < (unsigned)v) ? t : v;
  t = __builtin_amdgcn_update_dpp(v, v, 0x118, 0xf, 0xf, false);
  v = ((unsigned)t < (unsigned)v) ? t : v;
  t = __builtin_amdgcn_update_dpp(v, v, 0x142, 0xf, 0xf, false);
  v = ((unsigned)t < (unsigned)v) ? t : v;
  t = __builtin_amdgcn_update_dpp(v, v, 0x143, 0xf, 0xf, false);
  v = ((unsigned)t < (unsigned)v) ? t : v;
  return (unsigned)__builtin_amdgcn_readlane(v, 63);   // lane 63 = global min
}

__launch_bounds__(NT, 1)
__global__ void hungarian_r10(const float* __restrict__ outs,
                              const float* __restrict__ tgts,
                              int* __restrict__ out) {
  const int b = blockIdx.x;
  const int tid = threadIdx.x;
  const int lane = tid & 63;
  const int wv = tid >> 6;

  __shared__ CD rowDat[T + 1];      // rowDat[r] = {u[r], tx[r-1], ty[r-1]}
  __shared__ short p[Q + 1];        // p[j]: row matched to col j (1-based), 0 free
  __shared__ uint4 pkA[2][NW];      // mailbox keys {khi, klo, idx, 0} (parity)
  __shared__ uint4 pkB[2][NW];      // mailbox cd   {u_lo, u_hi, tx, ty} (parity)
  __shared__ int ansArr[T];
  __shared__ double s_rv[NW];
  __shared__ float sh_f;
  __shared__ CD cdSlot[KPT][NT];    // epilogue cd scatter: [k][owner], tx=-2 = never written
  __shared__ double vdelta[KPT][NT];// epilogue v scatter: [k][owner], 0.0 = no update

  const size_t qbase = (size_t)b * Q;
  const size_t tbase = (size_t)b * T;

  // ---- stage per-thread column data (fixed mapping j = 1 + tid + k*256) ----
  float xs[KPT], qx[KPT], qy[KPT];
#pragma unroll
  for (int k = 0; k < KPT; ++k) {
    const size_t o = (qbase + tid + k * NT) * 3;
    xs[k] = outs[o];
    qx[k] = outs[o + 1];
    qy[k] = outs[o + 2];
  }
  {
    const size_t o = (tbase + tid) * 3;   // T == NT: one target per thread
    rowDat[tid + 1].tx = tgts[o + 1];
    rowDat[tid + 1].ty = tgts[o + 2];
    rowDat[tid + 1].u = 0.0;
    if (tid == 0) { rowDat[0].tx = 0.f; rowDat[0].ty = 0.f; rowDat[0].u = 0.0; }
  }

  // ---- softmax over Q logits (bitwise-identical to the R2-passing tree) ----
  float lmax = xs[0];
#pragma unroll
  for (int k = 1; k < KPT; ++k) lmax = fmaxf(lmax, xs[k]);
  for (int off = 32; off > 0; off >>= 1) lmax = fmaxf(lmax, __shfl_down(lmax, off));
  if ((tid & 63) == 0) s_rv[tid >> 6] = (double)lmax;
  __syncthreads();
  if (tid == 0) {
    float m2 = (float)s_rv[0];
    for (int w = 1; w < NW; ++w) m2 = fmaxf(m2, (float)s_rv[w]);
    sh_f = m2;
  }
  __syncthreads();
  const float smax = sh_f;
  float ex[KPT];
  float lsum = 0.f;
#pragma unroll
  for (int k = 0; k < KPT; ++k) { ex[k] = expf(xs[k] - smax); lsum += ex[k]; }
  for (int off = 32; off > 0; off >>= 1) lsum += __shfl_down(lsum, off);
  if ((tid & 63) == 0) s_rv[tid >> 6] = (double)lsum;
  __syncthreads();
  if (tid == 0) {
    float s2 = 0.f;
    for (int w = 0; w < NW; ++w) s2 += (float)s_rv[w];
    sh_f = s2;
  }
  __syncthreads();
  const float ssum = sh_f;
  float np_[KPT];
#pragma unroll
  for (int k = 0; k < KPT; ++k) np_[k] = -(ex[k] / ssum);

  // ---- init state ----
  for (int j = tid; j <= Q; j += NT) p[j] = 0;
  double vreg[KPT];                 // v[j] for this thread's 8 columns
  double cdu[KPT];                  // u[p[j]] cache (register colDat)
  float cdx[KPT], cdy[KPT];         // tx/ty[p[j]-1] cache; -1.0f = FREE column
#pragma unroll
  for (int k = 0; k < KPT; ++k) {
    vreg[k] = 0.0;
    cdu[k] = 0.0; cdx[k] = -1.0f; cdy[k] = 0.0f;
    vdelta[k][tid] = 0.0;
    CD z; z.u = 0.0; z.tx = -2.0f; z.ty = 0.0f;   // sentinel: never written
    cdSlot[k][tid] = z;
  }
  __syncthreads();

  // ---- main loop over rows ----
  for (int i = 1; i <= T; ++i) {
    unsigned usedMask = 0;
    double D = 0.0;
    int i0 = i;
    double ui0 = rowDat[i].u;
    float tX = rowDat[i].tx, tY = rowDat[i].ty;
    int s = 0, S;
    int j1v = 0;                         // j1 of the previous step (0 at s=0)
    int recRow = 0, recCol = 0, recPrev = 0;   // thread t records step t
    double recU = 0.0, recD = 0.0;
    float recTX = 0.f, recTY = 0.f;

    for (;;) {
      // record this step's pre-state on thread s (off the dependency spine);
      // recPrev = column selected at step s-1 (for the v-delta scatter)
      if (tid == s) {
        recRow = i0; recU = ui0; recTX = tX; recTY = tY; recD = D; recPrev = j1v;
      }

      // scan my 8 unused columns: cur = ((double)cf - u[i0]) - v[j]
      double cv[KPT];
#pragma unroll
      for (int k = 0; k < KPT; ++k) {
        const float cf = fabsf(qx[k] - tX) + fabsf(qy[k] - tY) + np_[k];
        double cur = ((double)cf - ui0) - vreg[k];
        if (usedMask & (1u << k)) cur = DINF;   // used => never wins
        cv[k] = cur;
      }
      // within-lane argmin: fmin tree for the value, then parallel ==-mask +
      // ctz => smallest k among exact equals (first occurrence; +/-0 match)
      const double m01 = fmin(cv[0], cv[1]), m23 = fmin(cv[2], cv[3]);
      const double m45 = fmin(cv[4], cv[5]), m67 = fmin(cv[6], cv[7]);
      const double m03 = fmin(m01, m23), m47 = fmin(m45, m67);
      double bval = fmin(m03, m47);
      unsigned emsk = 0;
#pragma unroll
      for (int k = 0; k < KPT; ++k) emsk |= (cv[k] == bval) ? (1u << k) : 0u;
      const int bk = (int)__builtin_ctz(emsk);   // emsk != 0 always
      const int bidx = 1 + tid + (bk << 8);

      // per-lane cd[bk] select (static cndmask tree; overlaps the DPP chain)
      const int b0 = bk & 1, b1 = (bk >> 1) & 1, b2 = (bk >> 2) & 1;
      const double uA = b0 ? cdu[1] : cdu[0], uB = b0 ? cdu[3] : cdu[2];
      const double uC = b0 ? cdu[5] : cdu[4], uD = b0 ? cdu[7] : cdu[6];
      const float xA = b0 ? cdx[1] : cdx[0], xB = b0 ? cdx[3] : cdx[2];
      const float xC = b0 ? cdx[5] : cdx[4], xD = b0 ? cdx[7] : cdx[6];
      const float yA = b0 ? cdy[1] : cdy[0], yB = b0 ? cdy[3] : cdy[2];
      const float yC = b0 ? cdy[5] : cdy[4], yD = b0 ? cdy[7] : cdy[6];
      const double uE = b1 ? uB : uA, uF = b1 ? uD : uC;
      const float xE = b1 ? xB : xA, xF = b1 ? xD : xC;
      const float yE = b1 ? yB : yA, yF = b1 ? yD : yC;
      const double csu = b2 ? uF : uE;
      const float csx = b2 ? xF : xE;
      const float csy = b2 ? yF : yE;

      // monotonic u64 bit-key of the per-lane winner (canonicalize -0 -> +0)
      bval += 0.0;
      const long long bb = __double_as_longlong(bval);
      const unsigned long long key = (unsigned long long)bb ^
          ((bb < 0) ? 0xFFFFFFFFFFFFFFFFull : 0x8000000000000000ull);
      const unsigned khi = (unsigned)(key >> 32);
      const unsigned klo = (unsigned)key;

      // wave argmin: DPP min on hi32, ballot for winner, exact ties slow path
      const unsigned minhi = wave_min_u32_dpp(khi);
      const unsigned long long mask = __ballot(khi == minhi);
      int wl;
      if (__popcll(mask) == 1) {
        wl = (int)__ffsll(mask) - 1;
      } else {
        unsigned wklo = 0xffffffffu; int widx = 0x7fffffff; wl = 0;
        unsigned long long mm = mask;
        while (mm) {
          const int l = (int)__ffsll(mm) - 1; mm &= mm - 1;
          const unsigned lo2 = (unsigned)__builtin_amdgcn_readlane((int)klo, l);
          const int ix2 = __builtin_amdgcn_readlane(bidx, l);
          if (lo2 < wklo || (lo2 == wklo && ix2 < widx)) {
            wklo = lo2; widx = ix2; wl = l;
          }
        }
      }
      // the WINNING LANE writes its own key+cd: no readlanes on the spine
      const int par = s & 1;
      if (lane == wl) {
        pkA[par][wv] = make_uint4(minhi, klo, (unsigned)bidx, 0u);
        const long long cl = __double_as_longlong(csu);
        pkB[par][wv] = make_uint4((unsigned)(unsigned long long)cl,
                                  (unsigned)((unsigned long long)cl >> 32),
                                  __float_as_uint(csx), __float_as_uint(csy));
      }
      __syncthreads();            // the only per-step barrier

      // read all 8 mailbox quads up front (independent, uniform-broadcast)
      const uint4 c0v = pkA[par][0];
      const uint4 c1v = pkA[par][1];
      const uint4 c2v = pkA[par][2];
      const uint4 c3v = pkA[par][3];
      const uint4 d0v = pkB[par][0];
      const uint4 d1v = pkB[par][1];
      const uint4 d2v = pkB[par][2];
      const uint4 d3v = pkB[par][3];

      // cross-wave pairwise tournament (left wins ties at every level ==
      // same winner as the left-to-right scan of R5-R9)
      const unsigned long long k0b = ((unsigned long long)c0v.x << 32) | c0v.y;
      const unsigned long long k1b = ((unsigned long long)c1v.x << 32) | c1v.y;
      const unsigned long long k2b = ((unsigned long long)c2v.x << 32) | c2v.y;
      const unsigned long long k3b = ((unsigned long long)c3v.x << 32) | c3v.y;
      const int j0b = (int)c0v.z, j1bb = (int)c1v.z;
      const int j2b = (int)c2v.z, j3b = (int)c3v.z;
      const double u0 = __longlong_as_double(
          (long long)(((unsigned long long)d0v.y << 32) | d0v.x));
      const double u1 = __longlong_as_double(
          (long long)(((unsigned long long)d1v.y << 32) | d1v.x));
      const double u2 = __longlong_as_double(
          (long long)(((unsigned long long)d2v.y << 32) | d2v.x));
      const double u3 = __longlong_as_double(
          (long long)(((unsigned long long)d3v.y << 32) | d3v.x));
      const float x0 = __uint_as_float(d0v.z), y0 = __uint_as_float(d0v.w);
      const float x1 = __uint_as_float(d1v.z), y1 = __uint_as_float(d1v.w);
      const float x2 = __uint_as_float(d2v.z), y2 = __uint_as_float(d2v.w);
      const float x3 = __uint_as_float(d3v.z), y3 = __uint_as_float(d3v.w);
      // level 1 (pairs 01 and 23, independent)
      const bool w01 = (k1b < k0b) || (k1b == k0b && j1bb < j0b);
      const unsigned long long k01 = w01 ? k1b : k0b;
      const int j01 = w01 ? j1bb : j0b;
      const bool w23 = (k3b < k2b) || (k3b == k2b && j3b < j2b);
      const unsigned long long k23 = w23 ? k3b : k2b;
      const int j23 = w23 ? j3b : j2b;
      // level 2 (final)
      const bool wf = (k23 < k01) || (k23 == k01 && j23 < j01);
      const unsigned long long bkk = wf ? k23 : k01;
      const int j1 = wf ? j23 : j01;          // selected column, 1-based
      // cd selection folded along the same tournament (depth 2)
      const double uAx = w01 ? u1 : u0, uBx = w23 ? u3 : u2;
      const float xAx = w01 ? x1 : x0, xBx = w23 ? x3 : x2;
      const float yAx = w01 ? y1 : y0, yBx = w23 ? y3 : y2;
      const double cdun = wf ? uBx : uAx;
      const float cdtx = wf ? xBx : xAx;
      const float cdty = wf ? yBx : yAx;

      // invert bit-key -> delta (bitwise identical on every thread)
      const long long db = (long long)((bkk & 0x8000000000000000ull)
                                           ? (bkk ^ 0x8000000000000000ull) : ~bkk);
      D += __longlong_as_double(db);
      if (tid == ((j1 - 1) & 255)) usedMask |= 1u << ((j1 - 1) >> 8);
      if (tid == s) recCol = j1;
      const int pj1 = (int)p[j1];   // off-path: feeds only next step's recorder
      j1v = j1;
      ++s;
      if (cdtx < 0.0f) { S = s; break; }   // free column => path complete
      ui0 = cdun; tX = cdtx; tY = cdty; i0 = pj1;
    }

    // ---- epilogue: O(path) deferred updates, fully parallel scatter ----
    __syncthreads();              // E: all waves done stepping
    const double Dfin = D;
    if (tid < S) {
      p[recCol] = (short)recRow;                  // augment (rows/cols distinct)
      const double unew = recU + (Dfin - recD);   // same single-add as R3-R9
      rowDat[recRow].u = unew;
      const int c = recCol - 1;
      CD c2; c2.u = unew; c2.tx = recTX; c2.ty = recTY;
      cdSlot[c >> 8][c & 255] = c2;               // cd refresh for the owner
      if (tid >= 1) {
        // column of step tid-1 receives -(Dfin - D_before_step_tid):
        // identical value to R9's  vreg[...] -= (Dfin - visD[sv])
        const int pc = recPrev - 1;
        vdelta[pc >> 8][pc & 255] = -(Dfin - recD);
      }
    }
    __syncthreads();              // F: scatter writes visible
    // owners apply their (<= 8) updates: contiguous, conflict-free reads.
    // vdelta: 0.0 add is a bitwise no-op (vreg never -0.0). cdSlot: stale
    // slots re-apply the values the registers already hold (idempotent),
    // so no sentinel reset write is needed.
#pragma unroll
    for (int k = 0; k < KPT; ++k) {
      const double dv = vdelta[k][tid];
      const CD sl = cdSlot[k][tid];
      vreg[k] += dv;
      vdelta[k][tid] = 0.0;
      const bool upd = (sl.tx > -1.5f);
      cdu[k] = upd ? sl.u : cdu[k];
      cdx[k] = upd ? sl.tx : cdx[k];
      cdy[k] = upd ? sl.ty : cdy[k];
    }
    // next row's search reads rowDat/p (ordered by F) and registers; pk
    // mailbox overwrites are ordered by the next step's own barrier chain
  }
  __syncthreads();

  // ---- extract assignment, rank-sort (distinct values), write int32 ----
  for (int j = 1 + tid; j <= Q; j += NT) {
    const int pi = (int)p[j];
    if (pi > 0) ansArr[pi - 1] = j - 1;
  }
  __syncthreads();
  const int a = ansArr[tid];
  int rank = 0;
  for (int t2 = 0; t2 < T; ++t2) rank += (ansArr[t2] < a) ? 1 : 0;
  out[(size_t)b * T + rank] = a;                      // row_ind (sorted query idx)
  out[(size_t)B * T + (size_t)b * T + rank] = tid;    // col_ind (target idx)
}

extern "C" void kernel_launch(void* const* d_in, const int* in_sizes, int n_in,
                              void* d_out, int out_size, void* d_ws, size_t ws_size,
                              hipStream_t stream) {
  const float* outs = (const float*)d_in[0];   // (8, 2048, 3) fp32
  const float* tgts = (const float*)d_in[1];   // (8, 256, 3) fp32
  int* out = (int*)d_out;                      // row_ind (8,256) ++ col_ind (8,256)
  hungarian_r10<<<B, NT, 0, stream>>>(outs, tgts, out);
}

// Round 2
// 861.400 us; speedup vs baseline: 1.3648x; 1.3648x over previous
//
#include <hip/hip_runtime.h>

// GPUHungarianMatcher R11 — exact replication of the reference's degenerate
// "_lsa" (minv reset every inner iteration => chain-Dijkstra). One block
// (4 waves) per batch. R11 = R9's step loop (validated spine: lane-0 mailbox,
// post-barrier colDat prefetch overlapping the key tournament) + ONE change:
// the per-row serial v-update loop (S iters x 2 dependent broadcast LDS reads,
// plus a runtime-indexed vreg store that risks scratch demotion) is replaced
// by a parallel delta scatter:
//   * path thread t records recPrev = column chosen at step t-1 (== visCol[t])
//     and already holds recD (== visD[t]); it writes ONE LDS slot
//     vdelta[recPrev-1] = Dfin - recD  (bitwise-identical value to R9's
//     vreg[...] -= (Dfin - visD[sv]) update).
//   * after barrier F, each owner applies its 8 fixed slots with STATIC
//     indices: vreg[k] -= vdelta[tid + k*256], then resets the slot to 0.0.
//     Unmatched slots hold 0.0 and x -= 0.0 is a bitwise no-op (also for -0).
//   * columns on an augmenting path are distinct => no scatter collision;
//     slot reset is ordered vs the next row's scatter by the next E barrier.
// visCol/visD are deleted; vreg is now only ever indexed by compile-time
// constants (no rule-#20 scratch hazard).
//
// Exactness invariants (unchanged from the R2-R9 absmax-0 lineage):
//  * cost fp32: fabsf(qx-tX)+fabsf(qy-tY)+np_, reduced fp64: ((double)cf-u)-v
//  * scans read only PRE-search u/v (path rows/cols distinct, p injective)
//  * argmin: fmin + smallest-k among exact equals (ctz of ==-mask; +/-0 both
//    compare equal) = np.argmin first occurrence
//  * pairwise tournament: left wins ties at every level => same winner as
//    the left-to-right scan (min + earliest index, keys lexicographic)
//  * u update: single add of prefix-difference on pre-search u (recU)
//  * v update: identical values, scatter/apply instead of serial loop
//  * softmax bitwise-identical to the R2 tree (same thread mapping)
//  * free-flag: colDat[j].tx = -1.0f iff column j unmatched (real tx >= 0)

constexpr int B = 8;
constexpr int Q = 2048;        // columns (queries)
constexpr int T = 256;         // rows (targets)
constexpr int NT = 256;        // threads per block (4 waves)
constexpr int KPT = Q / NT;    // 8 columns per thread, j = 1 + tid + k*256
constexpr int NW = NT / 64;
constexpr double DINF = 1e300;

struct __align__(16) CD { double u; float tx, ty; };   // one ds_read_b128

__device__ __forceinline__ unsigned wave_min_u32_dpp(unsigned a) {
  // full-wave u32 min: row_shr 1,2,4,8 then row_bcast15, row_bcast31;
  // invalid source lanes keep old (bound_ctrl=false, masks 0xf) = identity.
  int v = (int)a, t;
  t = __builtin_amdgcn_update_dpp(v, v, 0x111, 0xf, 0xf, false);
  v = ((unsigned)t < (unsigned)v) ? t : v;
  t = __builtin_amdgcn_update_dpp(v, v, 0x112, 0xf, 0xf, false);
  v = ((unsigned)t < (unsigned)v) ? t : v;
  t = __builtin_amdgcn_update_dpp(v, v, 0x114, 0xf, 0xf, false);
  v = ((unsigned)t < (unsigned)v) ? t : v;
  t = __builtin_amdgcn_update_dpp(v, v, 0x118, 0xf, 0xf, false);
  v = ((unsigned)t < (unsigned)v) ? t : v;
  t = __builtin_amdgcn_update_dpp(v, v, 0x142, 0xf, 0xf, false);
  v = ((unsigned)t < (unsigned)v) ? t : v;
  t = __builtin_amdgcn_update_dpp(v, v, 0x143, 0xf, 0xf, false);
  v = ((unsigned)t < (unsigned)v) ? t : v;
  return (unsigned)__builtin_amdgcn_readlane(v, 63);   // lane 63 = global min
}

__launch_bounds__(NT, 1)
__global__ void hungarian_r11(const float* __restrict__ outs,
                              const float* __restrict__ tgts,
                              int* __restrict__ out) {
  const int b = blockIdx.x;
  const int tid = threadIdx.x;
  const int lane = tid & 63;
  const int wv = tid >> 6;

  __shared__ CD colDat[Q + 1];      // colDat[j] = {u[p[j]], tx[p[j]-1], ty[p[j]-1]}
                                    // tx = -1.0f marks a FREE column
  __shared__ CD rowDat[T + 1];      // rowDat[r] = {u[r], tx[r-1], ty[r-1]}
  __shared__ short p[Q + 1];        // p[j]: row matched to col j (1-based), 0 free
  __shared__ uint4 pk[2][NW];       // packed mailbox {khi, klo, idx, 0} (parity)
  __shared__ double vdelta[Q];      // per-column v-delta scatter; 0.0 = no update
  __shared__ int ansArr[T];
  __shared__ double s_rv[NW];
  __shared__ float sh_f;

  const size_t qbase = (size_t)b * Q;
  const size_t tbase = (size_t)b * T;

  // ---- stage per-thread column data (fixed mapping j = 1 + tid + k*256) ----
  float xs[KPT], qx[KPT], qy[KPT];
#pragma unroll
  for (int k = 0; k < KPT; ++k) {
    const size_t o = (qbase + tid + k * NT) * 3;
    xs[k] = outs[o];
    qx[k] = outs[o + 1];
    qy[k] = outs[o + 2];
  }
  {
    const size_t o = (tbase + tid) * 3;   // T == NT: one target per thread
    rowDat[tid + 1].tx = tgts[o + 1];
    rowDat[tid + 1].ty = tgts[o + 2];
    rowDat[tid + 1].u = 0.0;
    if (tid == 0) { rowDat[0].tx = 0.f; rowDat[0].ty = 0.f; rowDat[0].u = 0.0; }
  }

  // ---- softmax over Q logits (bitwise-identical to the R2-passing tree) ----
  float lmax = xs[0];
#pragma unroll
  for (int k = 1; k < KPT; ++k) lmax = fmaxf(lmax, xs[k]);
  for (int off = 32; off > 0; off >>= 1) lmax = fmaxf(lmax, __shfl_down(lmax, off));
  if ((tid & 63) == 0) s_rv[tid >> 6] = (double)lmax;
  __syncthreads();
  if (tid == 0) {
    float m2 = (float)s_rv[0];
    for (int w = 1; w < NW; ++w) m2 = fmaxf(m2, (float)s_rv[w]);
    sh_f = m2;
  }
  __syncthreads();
  const float smax = sh_f;
  float ex[KPT];
  float lsum = 0.f;
#pragma unroll
  for (int k = 0; k < KPT; ++k) { ex[k] = expf(xs[k] - smax); lsum += ex[k]; }
  for (int off = 32; off > 0; off >>= 1) lsum += __shfl_down(lsum, off);
  if ((tid & 63) == 0) s_rv[tid >> 6] = (double)lsum;
  __syncthreads();
  if (tid == 0) {
    float s2 = 0.f;
    for (int w = 0; w < NW; ++w) s2 += (float)s_rv[w];
    sh_f = s2;
  }
  __syncthreads();
  const float ssum = sh_f;
  float np_[KPT];
#pragma unroll
  for (int k = 0; k < KPT; ++k) np_[k] = -(ex[k] / ssum);

  // ---- init state ----
  for (int j = tid; j <= Q; j += NT) {
    p[j] = 0;
    CD c0; c0.u = 0.0; c0.tx = -1.0f; c0.ty = 0.0f;   // all columns free
    colDat[j] = c0;
  }
  double vreg[KPT];   // v[j] for this thread's 8 columns (static indices only)
#pragma unroll
  for (int k = 0; k < KPT; ++k) {
    vreg[k] = 0.0;
    vdelta[tid + (k << 8)] = 0.0;
  }
  __syncthreads();

  // ---- main loop over rows ----
  for (int i = 1; i <= T; ++i) {
    unsigned usedMask = 0;
    double D = 0.0;
    int i0 = i;
    double ui0 = rowDat[i].u;
    float tX = rowDat[i].tx, tY = rowDat[i].ty;
    int s = 0, S;
    int j1v = 0;                         // column selected at the previous step
    int recRow = 0, recCol = 0, recPrev = 0;   // thread t records step t's state
    double recU = 0.0, recD = 0.0;
    float recTX = 0.f, recTY = 0.f;

    for (;;) {
      // record this step's pre-state on thread s (off the dependency spine);
      // recPrev = column selected at step s-1 (== R9's visCol[s])
      if (tid == s) {
        recRow = i0; recU = ui0; recTX = tX; recTY = tY; recD = D; recPrev = j1v;
      }

      // scan my 8 unused columns: cur = ((double)cf - u[i0]) - v[j]
      double cv[KPT];
#pragma unroll
      for (int k = 0; k < KPT; ++k) {
        const float cf = fabsf(qx[k] - tX) + fabsf(qy[k] - tY) + np_[k];
        double cur = ((double)cf - ui0) - vreg[k];
        if (usedMask & (1u << k)) cur = DINF;   // used => never wins
        cv[k] = cur;
      }
      // within-lane argmin: fmin tree for the value, then parallel ==-mask +
      // ctz => smallest k among exact equals (first occurrence; +/-0 match)
      const double m01 = fmin(cv[0], cv[1]), m23 = fmin(cv[2], cv[3]);
      const double m45 = fmin(cv[4], cv[5]), m67 = fmin(cv[6], cv[7]);
      const double m03 = fmin(m01, m23), m47 = fmin(m45, m67);
      double bval = fmin(m03, m47);
      unsigned emsk = 0;
#pragma unroll
      for (int k = 0; k < KPT; ++k) emsk |= (cv[k] == bval) ? (1u << k) : 0u;
      const int bk = (int)__builtin_ctz(emsk);   // emsk != 0 always
      int bidx = 1 + tid + (bk << 8);

      // monotonic u64 bit-key of the per-lane winner (canonicalize -0 -> +0)
      bval += 0.0;
      const long long bb = __double_as_longlong(bval);
      const unsigned long long key = (unsigned long long)bb ^
          ((bb < 0) ? 0xFFFFFFFFFFFFFFFFull : 0x8000000000000000ull);
      const unsigned khi = (unsigned)(key >> 32);
      const unsigned klo = (unsigned)key;

      // wave argmin: DPP min on hi32, ballot for winner, exact ties slow path
      const unsigned minhi = wave_min_u32_dpp(khi);
      const unsigned long long mask = __ballot(khi == minhi);
      unsigned wklo; int widx;
      if (__popcll(mask) == 1) {
        const int wl = (int)__ffsll(mask) - 1;
        wklo = (unsigned)__builtin_amdgcn_readlane((int)klo, wl);
        widx = __builtin_amdgcn_readlane(bidx, wl);
      } else {
        wklo = 0xffffffffu; widx = 0x7fffffff;
        unsigned long long mm = mask;
        while (mm) {
          const int l = (int)__ffsll(mm) - 1; mm &= mm - 1;
          const unsigned lo2 = (unsigned)__builtin_amdgcn_readlane((int)klo, l);
          const int ix2 = __builtin_amdgcn_readlane(bidx, l);
          if (lo2 < wklo || (lo2 == wklo && ix2 < widx)) { wklo = lo2; widx = ix2; }
        }
      }
      const int par = s & 1;
      if (lane == 0) pk[par][wv] = make_uint4(minhi, wklo, (unsigned)widx, 0u);
      __syncthreads();            // the only per-step barrier

      // read the 4 packed candidates, then IMMEDIATELY prefetch their colDat
      const uint4 c0v = pk[par][0];
      const uint4 c1v = pk[par][1];
      const uint4 c2v = pk[par][2];
      const uint4 c3v = pk[par][3];
      const CD cd0 = colDat[(int)c0v.z];   // prefetch: latency overlaps combine
      const CD cd1 = colDat[(int)c1v.z];
      const CD cd2 = colDat[(int)c2v.z];
      const CD cd3 = colDat[(int)c3v.z];

      // cross-wave pairwise tournament (left wins ties at every level ==
      // same winner as the left-to-right scan of R5-R9)
      const unsigned long long k0b = ((unsigned long long)c0v.x << 32) | c0v.y;
      const unsigned long long k1b = ((unsigned long long)c1v.x << 32) | c1v.y;
      const unsigned long long k2b = ((unsigned long long)c2v.x << 32) | c2v.y;
      const unsigned long long k3b = ((unsigned long long)c3v.x << 32) | c3v.y;
      const int j0b = (int)c0v.z, j1bb = (int)c1v.z;
      const int j2b = (int)c2v.z, j3b = (int)c3v.z;
      // level 1 (pairs 01 and 23, independent)
      const bool w01 = (k1b < k0b) || (k1b == k0b && j1bb < j0b);
      const unsigned long long k01 = w01 ? k1b : k0b;
      const int j01 = w01 ? j1bb : j0b;
      const bool w23 = (k3b < k2b) || (k3b == k2b && j3b < j2b);
      const unsigned long long k23 = w23 ? k3b : k2b;
      const int j23 = w23 ? j3b : j2b;
      // level 2 (final)
      const bool wf = (k23 < k01) || (k23 == k01 && j23 < j01);
      const unsigned long long bkk = wf ? k23 : k01;
      const int j1 = wf ? j23 : j01;          // selected column, 1-based
      // CD selection folded along the same tournament (depth 2)
      CD cdA; cdA.u = w01 ? cd1.u : cd0.u;
      cdA.tx = w01 ? cd1.tx : cd0.tx; cdA.ty = w01 ? cd1.ty : cd0.ty;
      CD cdB; cdB.u = w23 ? cd3.u : cd2.u;
      cdB.tx = w23 ? cd3.tx : cd2.tx; cdB.ty = w23 ? cd3.ty : cd2.ty;
      CD cd; cd.u = wf ? cdB.u : cdA.u;
      cd.tx = wf ? cdB.tx : cdA.tx; cd.ty = wf ? cdB.ty : cdA.ty;

      // invert bit-key -> delta (bitwise identical on every thread)
      const long long db = (long long)((bkk & 0x8000000000000000ull)
                                           ? (bkk ^ 0x8000000000000000ull) : ~bkk);
      D += __longlong_as_double(db);
      if (tid == ((j1 - 1) & 255)) usedMask |= 1u << ((j1 - 1) >> 8);
      if (tid == s) recCol = j1;
      const int pj1 = (int)p[j1];   // off-path: feeds only next step's recorder
      j1v = j1;
      ++s;
      if (cd.tx < 0.0f) { S = s; break; }   // free column => path complete
      ui0 = cd.u; tX = cd.tx; tY = cd.ty; i0 = pj1;
    }

    // ---- epilogue: O(path) deferred updates from recorded registers ----
    __syncthreads();              // E: all waves done stepping
    const double Dfin = D;
    if (tid < S) {
      p[recCol] = (short)recRow;                  // augment (rows/cols distinct)
      const double unew = recU + (Dfin - recD);   // same single-add as R3-R9
      rowDat[recRow].u = unew;
      CD c2; c2.u = unew; c2.tx = recTX; c2.ty = recTY;
      colDat[recCol] = c2;                        // refresh cache (tx >= 0)
      if (tid >= 1) {
        // column of step tid-1 (== R9's visCol[tid]) receives Dfin - recD
        // (== Dfin - visD[tid]); path columns distinct => no collision
        vdelta[recPrev - 1] = Dfin - recD;
      }
    }
    __syncthreads();              // F: epilogue writes visible
    // owners apply their 8 slots: static indices, stride-8B conflict-free
    // reads; 0.0 slots are bitwise no-ops (x -= 0.0 == x, incl. -0.0).
#pragma unroll
    for (int k = 0; k < KPT; ++k) {
      const double dv = vdelta[tid + (k << 8)];
      vreg[k] -= dv;
      vdelta[tid + (k << 8)] = 0.0;   // reset; ordered vs next scatter by E
    }
    // next row's search reads (rowDat/colDat/p) ordered by F; vdelta slots
    // are re-written only after the next E barrier
  }
  __syncthreads();

  // ---- extract assignment, rank-sort (distinct values), write int32 ----
  for (int j = 1 + tid; j <= Q; j += NT) {
    const int pi = (int)p[j];
    if (pi > 0) ansArr[pi - 1] = j - 1;
  }
  __syncthreads();
  const int a = ansArr[tid];
  int rank = 0;
  for (int t2 = 0; t2 < T; ++t2) rank += (ansArr[t2] < a) ? 1 : 0;
  out[(size_t)b * T + rank] = a;                      // row_ind (sorted query idx)
  out[(size_t)B * T + (size_t)b * T + rank] = tid;    // col_ind (target idx)
}

extern "C" void kernel_launch(void* const* d_in, const int* in_sizes, int n_in,
                              void* d_out, int out_size, void* d_ws, size_t ws_size,
                              hipStream_t stream) {
  const float* outs = (const float*)d_in[0];   // (8, 2048, 3) fp32
  const float* tgts = (const float*)d_in[1];   // (8, 256, 3) fp32
  int* out = (int*)d_out;                      // row_ind (8,256) ++ col_ind (8,256)
  hungarian_r11<<<B, NT, 0, stream>>>(outs, tgts, out);
}